// Round 17
// baseline (921.913 us; speedup 1.0000x reference)
//
#include <hip/hip_runtime.h>
#include <hip/hip_fp16.h>
#include <math.h>

#define DIM 64
#define IN_DIM 25
#define B_GRAPHS 1024
#define STEPS 3
#define GPB 2             // graphs per set2set block (TWO waves per graph)
#define SCCAP 160         // cached scores per graph (cnt max ~140)
#define BSHIFT 7          // 128 dsts per bucket
#define NBUCK_MAX 1024
#define BCAP 3072         // arena slots per bucket (mean 2046, +22 sigma)
#define CHUNK_A 4096      // edges per pass-A block (16 per thread)
#define ASTRIDE 68        // aggr row stride (floats): pad 64->68 kills MFMA-read
                          // 16-way bank conflict; ds_add stays conflict-free

typedef _Float16 half8 __attribute__((ext_vector_type(8)));
typedef float    f32x4 __attribute__((ext_vector_type(4)));

__device__ __forceinline__ float wave_sum(float v) {
    #pragma unroll
    for (int o = 32; o > 0; o >>= 1) v += __shfl_xor(v, o, 64);
    return v;
}

// Prep mega-kernel, independent sections by blockIdx:
//   [0, fillB)          : bucket-partition edges -> packed arena (LDS hist,
//                         one global atomic per bucket per block)
//   [fillB, fillB+nbL)  : lin0 -> h0h (fp16)
//   [fillB+nbL, +nb256) : per-graph bounds via boundary writes
__global__ void prep_kernel(const float* __restrict__ x,
                            const float* __restrict__ W,
                            const float* __restrict__ b,
                            __half* __restrict__ h0h,
                            const int* __restrict__ ei, int E,
                            const int* __restrict__ batch, int N,
                            int* __restrict__ gcur,
                            unsigned* __restrict__ arena,
                            int* __restrict__ startb, int* __restrict__ endb,
                            int fillB, int nbL, int nbuck) {
    int bi = blockIdx.x;
    if (bi < fillB) {
        __shared__ int hist[NBUCK_MAX];
        int tid = threadIdx.x;
        for (int t = tid; t < nbuck; t += 256) hist[t] = 0;
        __syncthreads();
        int e0 = bi * CHUNK_A;
        int dstr[16], lofs[16];
        #pragma unroll
        for (int k = 0; k < 16; ++k) {
            int e = e0 + k * 256 + tid;
            dstr[k] = -1;
            if (e < E) {
                int d = ei[E + e];
                dstr[k] = d;
                lofs[k] = atomicAdd(&hist[d >> BSHIFT], 1);   // LDS atomic
            }
        }
        __syncthreads();
        for (int t = tid; t < nbuck; t += 256)
            hist[t] = atomicAdd(&gcur[t], hist[t]);           // 1 global/bucket
        __syncthreads();
        #pragma unroll
        for (int k = 0; k < 16; ++k) {
            int d = dstr[k];
            if (d >= 0) {
                int e = e0 + k * 256 + tid;
                unsigned src = (unsigned)ei[e];
                int bk = d >> BSHIFT;
                int pos = hist[bk] + lofs[k];
                if (pos < BCAP)
                    arena[(size_t)bk * BCAP + pos] =
                        (src << BSHIFT) | (unsigned)(d & ((1 << BSHIFT) - 1));
            }
        }
    } else if (bi < fillB + nbL) {
        int grp  = threadIdx.x >> 6;
        int lane = threadIdx.x & 63;
        int n = (bi - fillB) * 4 + grp;
        if (n >= N) return;
        float acc = b[lane];
        const float* xr = x + (size_t)n * IN_DIM;
        #pragma unroll
        for (int k = 0; k < IN_DIM; ++k)
            acc += xr[k] * W[k * DIM + lane];
        h0h[(size_t)n * DIM + lane] = __float2half(fmaxf(acc, 0.f));
    } else {
        int i = (bi - fillB - nbL) * 256 + threadIdx.x;
        if (i >= N) return;
        int g = batch[i];
        if (i == 0) {
            startb[g] = 0;
        } else if (batch[i - 1] != g) {
            startb[g] = i;
            endb[batch[i - 1]] = i;
        }
        if (i == N - 1) endb[g] = N;
    }
}

// Fused bucket-aggregate + GIN MFMA. One block per bucket (128 dsts).
// LDS aggr tile (fp32) init w/ self term; per edge: one coalesced 128 B
// wave-read of h0h[src] + one ds_add_f32/lane (no csr, no HBM atomics).
// Epilogue: v_mfma_f32_16x16x32_f16, A from LDS (converted), B = W tile.
__global__ void gin_bucket_kernel(const __half* __restrict__ h0h,
                                  const unsigned* __restrict__ arena,
                                  const int* __restrict__ gcur,
                                  const float* __restrict__ W,
                                  const float* __restrict__ bias,
                                  __half* __restrict__ h1h, int N) {
    int bk   = blockIdx.x;
    int tid  = threadIdx.x;
    int wid  = tid >> 6;
    int lane = tid & 63;
    int sub  = lane & 15;
    int quad = lane >> 4;
    __shared__ __align__(16) float aggr[128][ASTRIDE];    // 34 KB

    int base = bk << BSHIFT;
    int rows = N - base;
    if (rows > 128) rows = 128;
    if (rows < 0) rows = 0;

    // B fragments (wave's 16-column tile of W) — overlaps the edge stream.
    half8 bfrag0, bfrag1;
    {
        int cb = wid * 16 + sub;
        #pragma unroll
        for (int j = 0; j < 8; ++j) {
            bfrag0[j] = (_Float16)W[(quad * 8 + j) * DIM + cb];
            bfrag1[j] = (_Float16)W[(32 + quad * 8 + j) * DIM + cb];
        }
    }
    float bias_l = bias[wid * 16 + sub];

    // init aggr rows with self term h0h[base+r]
    for (int r = wid; r < rows; r += 4)
        aggr[r][lane] = __half2float(h0h[(size_t)(base + r) * DIM + lane]);
    __syncthreads();

    // edge stream: wave-partitioned range of this bucket's packed edges
    int nE = gcur[bk];
    if (nE > BCAP) nE = BCAP;
    const unsigned* ap = arena + (size_t)bk * BCAP;
    int per    = (nE + 3) >> 2;
    int wstart = wid * per;
    int wend   = wstart + per;
    if (wend > nE) wend = nE;
    for (int c = wstart; c < wend; c += 64) {
        int m = wend - c;
        if (m > 64) m = 64;
        unsigned pk = (c + lane < wend) ? ap[c + lane] : 0u;
        for (int j = 0; j < m; j += 8) {
            float vals[8];
            int   dls[8];
            #pragma unroll
            for (int k = 0; k < 8; ++k) {
                unsigned p = __shfl(pk, j + k, 64);
                bool vd = (j + k) < m;
                int src = vd ? (int)(p >> BSHIFT) : 0;
                dls[k] = vd ? (int)(p & ((1u << BSHIFT) - 1)) : -1;
                vals[k] = __half2float(h0h[(size_t)src * DIM + lane]);
            }
            #pragma unroll
            for (int k = 0; k < 8; ++k)
                if (dls[k] >= 0) atomicAdd(&aggr[dls[k]][lane], vals[k]);
        }
    }
    __syncthreads();

    // MFMA epilogue: 8 node-tiles x (wave's 16-column slice)
    #pragma unroll
    for (int t = 0; t < 8; ++t) {
        int r0 = t * 16;
        if (r0 >= rows) break;
        const float* arow0 = &aggr[r0 + sub][quad * 8];
        half8 afrag0, afrag1;
        {
            f32x4 f0 = *(const f32x4*)(arow0);
            f32x4 f1 = *(const f32x4*)(arow0 + 4);
            f32x4 f2 = *(const f32x4*)(arow0 + 32);
            f32x4 f3 = *(const f32x4*)(arow0 + 36);
            #pragma unroll
            for (int j = 0; j < 4; ++j) {
                afrag0[j]     = (_Float16)f0[j];
                afrag0[4 + j] = (_Float16)f1[j];
                afrag1[j]     = (_Float16)f2[j];
                afrag1[4 + j] = (_Float16)f3[j];
            }
        }
        f32x4 acc = {0.f, 0.f, 0.f, 0.f};
        acc = __builtin_amdgcn_mfma_f32_16x16x32_f16(afrag0, bfrag0, acc, 0, 0, 0);
        acc = __builtin_amdgcn_mfma_f32_16x16x32_f16(afrag1, bfrag1, acc, 0, 0, 0);
        #pragma unroll
        for (int r = 0; r < 4; ++r) {
            int n = base + r0 + quad * 4 + r;
            if (n < N) {
                float v = fmaxf(acc[r] + bias_l, 0.f);
                h1h[(size_t)n * DIM + wid * 16 + sub] = __float2half(v);
            }
        }
    }
}

// Set2Set (3 steps) + head. GPB=2 graphs/block, two waves per graph
// (512 blocks -> 2 blocks/CU). Unchanged from R15.
__global__ __launch_bounds__(256)
void set2set_fused_kernel(const __half* __restrict__ h1h,
                          const float* __restrict__ W_ih,
                          const float* __restrict__ W_hh,
                          const float* __restrict__ b_ih,
                          const float* __restrict__ b_hh,
                          const int* __restrict__ startb,
                          const int* __restrict__ endb,
                          const float* __restrict__ lin1_W,
                          const float* __restrict__ lin1_b,
                          const float* __restrict__ lin2_W,
                          const float* __restrict__ lin2_b,
                          float* __restrict__ out) {
    int g0  = blockIdx.x * GPB;
    int tid = threadIdx.x;
    __shared__ __align__(16) float qsbuf[GPB][2 * DIM];
    __shared__ float csbuf[GPB][DIM];
    __shared__ float gatesL[GPB][4 * DIM];
    __shared__ float scL[GPB][SCCAP];
    __shared__ float pmax[GPB][2];
    __shared__ float pden[GPB][2];
    __shared__ __align__(16) float4 pr[GPB][2][16];

    int wid  = tid >> 6;
    int myg  = wid >> 1;
    int wh   = wid & 1;
    int lane = tid & 63;
    int stg  = startb[g0 + myg];
    int cntg = endb[g0 + myg] - stg;
    if (cntg < 0) cntg = 0;

    for (int f = tid; f < GPB * 2 * DIM; f += 256) ((float*)qsbuf)[f] = 0.f;
    for (int f = tid; f < GPB * DIM; f += 256) ((float*)csbuf)[f] = 0.f;
    float bias_t = b_ih[tid] + b_hh[tid];
    __syncthreads();

    int sub   = lane & 15;
    int jslot = lane >> 4;
    int i0    = wh * 4 + jslot;

    for (int step = 0; step < STEPS; ++step) {
        {
            float a0 = bias_t, a1 = bias_t;
            const float4* wi = (const float4*)(W_ih + (size_t)tid * 2 * DIM);
            const float4* q0 = (const float4*)qsbuf[0];
            const float4* q1 = (const float4*)qsbuf[1];
            #pragma unroll 8
            for (int k = 0; k < 2 * DIM / 4; ++k) {
                float4 w = wi[k];
                float4 v0 = q0[k], v1 = q1[k];
                a0 += w.x * v0.x + w.y * v0.y + w.z * v0.z + w.w * v0.w;
                a1 += w.x * v1.x + w.y * v1.y + w.z * v1.z + w.w * v1.w;
            }
            const float4* wh4 = (const float4*)(W_hh + (size_t)tid * DIM);
            #pragma unroll 8
            for (int k = 0; k < DIM / 4; ++k) {
                float4 w = wh4[k];
                float4 v0 = q0[k], v1 = q1[k];
                a0 += w.x * v0.x + w.y * v0.y + w.z * v0.z + w.w * v0.w;
                a1 += w.x * v1.x + w.y * v1.y + w.z * v1.z + w.w * v1.w;
            }
            gatesL[0][tid] = a0; gatesL[1][tid] = a1;
        }
        __syncthreads();
        if (tid < GPB * DIM) {
            int g = tid >> 6, d = tid & 63;
            float ig = gatesL[g][d];
            float fg = gatesL[g][DIM + d];
            float gg = gatesL[g][2 * DIM + d];
            float og = gatesL[g][3 * DIM + d];
            float si = 1.f / (1.f + __expf(-ig));
            float sf = 1.f / (1.f + __expf(-fg));
            float so = 1.f / (1.f + __expf(-og));
            float cn = sf * csbuf[g][d] + si * tanhf(gg);
            float hn = so * tanhf(cn);
            csbuf[g][d] = cn;
            qsbuf[g][d] = hn;
        }
        __syncthreads();

        const float4 q4 = *(const float4*)(&qsbuf[myg][4 * sub]);

        float gmax = -INFINITY;
        for (int i = i0; i < cntg; i += 8) {
            const __half2* p =
                (const __half2*)(h1h + (size_t)(stg + i) * DIM + 4 * sub);
            float2 f0 = __half22float2(p[0]), f1 = __half22float2(p[1]);
            float pdot = f0.x * q4.x + f0.y * q4.y + f1.x * q4.z + f1.y * q4.w;
            pdot += __shfl_xor(pdot, 1, 64);
            pdot += __shfl_xor(pdot, 2, 64);
            pdot += __shfl_xor(pdot, 4, 64);
            pdot += __shfl_xor(pdot, 8, 64);
            if (sub == 0 && i < SCCAP) scL[myg][i] = pdot;
            gmax = fmaxf(gmax, pdot);
        }
        gmax = fmaxf(gmax, __shfl_xor(gmax, 16, 64));
        gmax = fmaxf(gmax, __shfl_xor(gmax, 32, 64));
        if (lane == 0) pmax[myg][wh] = gmax;
        __syncthreads();
        float m = fmaxf(pmax[myg][0], pmax[myg][1]);

        float4 racc = {0.f, 0.f, 0.f, 0.f};
        float den = 0.f;
        for (int i = i0; i < cntg; i += 8) {
            const __half2* p =
                (const __half2*)(h1h + (size_t)(stg + i) * DIM + 4 * sub);
            float2 f0 = __half22float2(p[0]), f1 = __half22float2(p[1]);
            float pdot;
            if (i < SCCAP) {
                pdot = scL[myg][i];
            } else {
                pdot = f0.x * q4.x + f0.y * q4.y + f1.x * q4.z + f1.y * q4.w;
                pdot += __shfl_xor(pdot, 1, 64);
                pdot += __shfl_xor(pdot, 2, 64);
                pdot += __shfl_xor(pdot, 4, 64);
                pdot += __shfl_xor(pdot, 8, 64);
            }
            float w = __expf(pdot - m);
            if (sub == 0) den += w;
            racc.x += w * f0.x; racc.y += w * f0.y;
            racc.z += w * f1.x; racc.w += w * f1.y;
        }
        racc.x += __shfl_xor(racc.x, 16, 64); racc.y += __shfl_xor(racc.y, 16, 64);
        racc.z += __shfl_xor(racc.z, 16, 64); racc.w += __shfl_xor(racc.w, 16, 64);
        racc.x += __shfl_xor(racc.x, 32, 64); racc.y += __shfl_xor(racc.y, 32, 64);
        racc.z += __shfl_xor(racc.z, 32, 64); racc.w += __shfl_xor(racc.w, 32, 64);
        den += __shfl_xor(den, 16, 64);
        den += __shfl_xor(den, 32, 64);
        if (jslot == 0) pr[myg][wh][sub] = racc;
        if (lane == 0) pden[myg][wh] = den;
        __syncthreads();
        if (wh == 0 && jslot == 0) {
            float4 rA = pr[myg][0][sub];
            float4 rB = pr[myg][1][sub];
            float dt = pden[myg][0] + pden[myg][1];
            if (dt == 0.f) dt = 1.f;
            float4 rv;
            rv.x = (rA.x + rB.x) / dt; rv.y = (rA.y + rB.y) / dt;
            rv.z = (rA.z + rB.z) / dt; rv.w = (rA.w + rB.w) / dt;
            *(float4*)(&qsbuf[myg][DIM + 4 * sub]) = rv;
        }
        __syncthreads();
    }

    if (wh == 0) {
        float acc = lin1_b[lane];
        const float* qv = qsbuf[myg];
        #pragma unroll 8
        for (int k = 0; k < 2 * DIM; ++k)
            acc += qv[k] * lin1_W[k * DIM + lane];
        acc = fmaxf(acc, 0.f);
        float v = acc * lin2_W[lane];
        v = wave_sum(v);
        if (lane == 0) out[g0 + myg] = v + lin2_b[0];
    }
}

extern "C" void kernel_launch(void* const* d_in, const int* in_sizes, int n_in,
                              void* d_out, int out_size, void* d_ws, size_t ws_size,
                              hipStream_t stream) {
    const float* x      = (const float*)d_in[0];
    const int*   ei     = (const int*)d_in[1];
    const int*   batch  = (const int*)d_in[2];
    const float* lin0_W = (const float*)d_in[3];
    const float* lin0_b = (const float*)d_in[4];
    const float* gin_W  = (const float*)d_in[5];
    const float* gin_b  = (const float*)d_in[6];
    const float* W_ih   = (const float*)d_in[7];
    const float* W_hh   = (const float*)d_in[8];
    const float* b_ih   = (const float*)d_in[9];
    const float* b_hh   = (const float*)d_in[10];
    const float* lin1_W = (const float*)d_in[11];
    const float* lin1_b = (const float*)d_in[12];
    const float* lin2_W = (const float*)d_in[13];
    const float* lin2_b = (const float*)d_in[14];
    float* out = (float*)d_out;

    const int N = in_sizes[2];        // 100000 nodes
    const int E = in_sizes[1] / 2;    // 1600000 edges

    char* ws = (char*)d_ws;
    size_t off = 0;
    auto take = [&](size_t bytes) -> char* {
        char* p = ws + off;
        off += (bytes + 255) & ~(size_t)255;
        return p;
    };
    int nbuck = (N + (1 << BSHIFT) - 1) >> BSHIFT;        // 782

    __half*   h0h   = (__half*)take((size_t)N * DIM * 2);
    __half*   h1h   = (__half*)take((size_t)N * DIM * 2);
    unsigned* arena = (unsigned*)take((size_t)nbuck * BCAP * 4);
    // ---- zeroed region start ----
    int* startb = (int*)take((size_t)B_GRAPHS * 4);
    int* endb   = (int*)take((size_t)B_GRAPHS * 4);
    int* gcur   = (int*)take((size_t)NBUCK_MAX * 4);
    // ---- zeroed region end ----
    size_t zero_bytes = (size_t)((char*)gcur - (char*)startb) + NBUCK_MAX * 4;
    hipMemsetAsync(startb, 0, zero_bytes, stream);

    int nb4   = (N + 3) / 4;
    int nb256 = (N + 255) / 256;
    int fillB = (E + CHUNK_A - 1) / CHUNK_A;

    hipLaunchKernelGGL(prep_kernel, dim3(fillB + nb4 + nb256), dim3(256), 0, stream,
                       x, lin0_W, lin0_b, h0h, ei, E, batch, N,
                       gcur, arena, startb, endb, fillB, nb4, nbuck);
    hipLaunchKernelGGL(gin_bucket_kernel, dim3(nbuck), dim3(256), 0, stream,
                       h0h, arena, gcur, gin_W, gin_b, h1h, N);
    hipLaunchKernelGGL(set2set_fused_kernel, dim3(B_GRAPHS / GPB), dim3(256), 0, stream,
                       h1h, W_ih, W_hh, b_ih, b_hh, startb, endb,
                       lin1_W, lin1_b, lin2_W, lin2_b, out);
}

// Round 18
// 295.370 us; speedup vs baseline: 3.1212x; 3.1212x over previous
//
#include <hip/hip_runtime.h>
#include <hip/hip_fp16.h>
#include <math.h>

#define DIM 64
#define IN_DIM 25
#define B_GRAPHS 1024
#define STEPS 3
#define GPB 2             // graphs per set2set block (TWO waves per graph)
#define SCCAP 160         // cached scores per graph (cnt max ~140)
#define BSHIFT 7          // 128 dsts per bucket
#define NBUCK_MAX 1024
#define BCAP 3072         // arena slots per bucket (mean 2046, +22 sigma)
#define CHUNK_A 4096      // edges per pass-A block (16 per thread)
#define ASTRIDE 68        // aggr row stride (floats): 2-way bank aliasing (free)

typedef _Float16 half8 __attribute__((ext_vector_type(8)));
typedef float    f32x4 __attribute__((ext_vector_type(4)));

__device__ __forceinline__ float wave_sum(float v) {
    #pragma unroll
    for (int o = 32; o > 0; o >>= 1) v += __shfl_xor(v, o, 64);
    return v;
}

// Prep mega-kernel, independent sections by blockIdx:
//   [0, fillB)          : bucket-partition edges -> packed arena
//   [fillB, fillB+nbL)  : lin0 -> h0h (fp16)
//   [fillB+nbL, +nb256) : per-graph bounds via boundary writes
__global__ void prep_kernel(const float* __restrict__ x,
                            const float* __restrict__ W,
                            const float* __restrict__ b,
                            __half* __restrict__ h0h,
                            const int* __restrict__ ei, int E,
                            const int* __restrict__ batch, int N,
                            int* __restrict__ gcur,
                            unsigned* __restrict__ arena,
                            int* __restrict__ startb, int* __restrict__ endb,
                            int fillB, int nbL, int nbuck) {
    int bi = blockIdx.x;
    if (bi < fillB) {
        __shared__ int hist[NBUCK_MAX];
        int tid = threadIdx.x;
        for (int t = tid; t < nbuck; t += 256) hist[t] = 0;
        __syncthreads();
        int e0 = bi * CHUNK_A;
        int dstr[16], lofs[16];
        #pragma unroll
        for (int k = 0; k < 16; ++k) {
            int e = e0 + k * 256 + tid;
            dstr[k] = -1;
            if (e < E) {
                int d = ei[E + e];
                dstr[k] = d;
                lofs[k] = atomicAdd(&hist[d >> BSHIFT], 1);   // int LDS atomic: cheap
            }
        }
        __syncthreads();
        for (int t = tid; t < nbuck; t += 256)
            hist[t] = atomicAdd(&gcur[t], hist[t]);           // 1 global/bucket
        __syncthreads();
        #pragma unroll
        for (int k = 0; k < 16; ++k) {
            int d = dstr[k];
            if (d >= 0) {
                int e = e0 + k * 256 + tid;
                unsigned src = (unsigned)ei[e];
                int bk = d >> BSHIFT;
                int pos = hist[bk] + lofs[k];
                if (pos < BCAP)
                    arena[(size_t)bk * BCAP + pos] =
                        (src << BSHIFT) | (unsigned)(d & ((1 << BSHIFT) - 1));
            }
        }
    } else if (bi < fillB + nbL) {
        int grp  = threadIdx.x >> 6;
        int lane = threadIdx.x & 63;
        int n = (bi - fillB) * 4 + grp;
        if (n >= N) return;
        float acc = b[lane];
        const float* xr = x + (size_t)n * IN_DIM;
        #pragma unroll
        for (int k = 0; k < IN_DIM; ++k)
            acc += xr[k] * W[k * DIM + lane];
        h0h[(size_t)n * DIM + lane] = __float2half(fmaxf(acc, 0.f));
    } else {
        int i = (bi - fillB - nbL) * 256 + threadIdx.x;
        if (i >= N) return;
        int g = batch[i];
        if (i == 0) {
            startb[g] = 0;
        } else if (batch[i - 1] != g) {
            startb[g] = i;
            endb[batch[i - 1]] = i;
        }
        if (i == N - 1) endb[g] = N;
    }
}

// Fused bucket-aggregate + GIN MFMA, ATOMIC-FREE (R17 fix).
// Wave w owns aggr rows dl%4==w. All waves scan the bucket's edges 64-wide;
// ballot-compact owned edges into a per-wave LDS queue; process queue in
// 8-wide batches: 8 coalesced 128 B h0h loads, then 8 plain LDS RMWs
// (owner-exclusive rows -> no atomics, no cross-wave hazards).
__global__ void gin_bucket_kernel(const __half* __restrict__ h0h,
                                  const unsigned* __restrict__ arena,
                                  const int* __restrict__ gcur,
                                  const float* __restrict__ W,
                                  const float* __restrict__ bias,
                                  __half* __restrict__ h1h, int N) {
    int bk   = blockIdx.x;
    int tid  = threadIdx.x;
    int wid  = tid >> 6;
    int lane = tid & 63;
    int sub  = lane & 15;
    int quad = lane >> 4;
    __shared__ __align__(16) float aggr[128][ASTRIDE];    // 34 KB
    __shared__ unsigned qlist[4][64];                     // per-wave queue, 1 KB

    int base = bk << BSHIFT;
    int rows = N - base;
    if (rows > 128) rows = 128;
    if (rows < 0) rows = 0;

    // B fragments (wave's 16-column tile of W) — overlaps the edge stream.
    half8 bfrag0, bfrag1;
    {
        int cb = wid * 16 + sub;
        #pragma unroll
        for (int j = 0; j < 8; ++j) {
            bfrag0[j] = (_Float16)W[(quad * 8 + j) * DIM + cb];
            bfrag1[j] = (_Float16)W[(32 + quad * 8 + j) * DIM + cb];
        }
    }
    float bias_l = bias[wid * 16 + sub];

    // init aggr rows with self term; wave w inits exactly the rows it owns
    for (int r = wid; r < rows; r += 4)
        aggr[r][lane] = __half2float(h0h[(size_t)(base + r) * DIM + lane]);

    int nE = gcur[bk];
    if (nE > BCAP) nE = BCAP;
    const unsigned* ap = arena + (size_t)bk * BCAP;

    for (int c = 0; c < nE; c += 64) {
        unsigned pk = 0u;
        bool own = false;
        if (c + lane < nE) {
            pk = ap[c + lane];
            own = ((pk & 3u) == (unsigned)wid);       // dl%4 == wid (dl = pk&127)
        }
        unsigned long long mask = __ballot(own);
        int idx = __popcll(mask & ((1ULL << lane) - 1ULL));
        if (own) qlist[wid][idx] = pk;
        int qn = __popcll(mask);
        // process this wave's queue in 8-wide batches
        for (int j = 0; j < qn; j += 8) {
            float vals[8];
            int   dls[8];
            #pragma unroll
            for (int k = 0; k < 8; ++k) {
                bool vd = (j + k) < qn;
                unsigned p = vd ? qlist[wid][j + k] : 0u;   // broadcast LDS read
                int src = vd ? (int)(p >> BSHIFT) : 0;
                dls[k] = vd ? (int)(p & ((1u << BSHIFT) - 1)) : -1;
                vals[k] = __half2float(h0h[(size_t)src * DIM + lane]);
            }
            #pragma unroll
            for (int k = 0; k < 8; ++k)
                if (dls[k] >= 0) aggr[dls[k]][lane] += vals[k];   // plain RMW
        }
    }
    __syncthreads();

    // MFMA epilogue: 8 node-tiles x (wave's 16-column slice)
    #pragma unroll
    for (int t = 0; t < 8; ++t) {
        int r0 = t * 16;
        if (r0 >= rows) break;
        const float* arow0 = &aggr[r0 + sub][quad * 8];
        half8 afrag0, afrag1;
        {
            f32x4 f0 = *(const f32x4*)(arow0);
            f32x4 f1 = *(const f32x4*)(arow0 + 4);
            f32x4 f2 = *(const f32x4*)(arow0 + 32);
            f32x4 f3 = *(const f32x4*)(arow0 + 36);
            #pragma unroll
            for (int j = 0; j < 4; ++j) {
                afrag0[j]     = (_Float16)f0[j];
                afrag0[4 + j] = (_Float16)f1[j];
                afrag1[j]     = (_Float16)f2[j];
                afrag1[4 + j] = (_Float16)f3[j];
            }
        }
        f32x4 acc = {0.f, 0.f, 0.f, 0.f};
        acc = __builtin_amdgcn_mfma_f32_16x16x32_f16(afrag0, bfrag0, acc, 0, 0, 0);
        acc = __builtin_amdgcn_mfma_f32_16x16x32_f16(afrag1, bfrag1, acc, 0, 0, 0);
        #pragma unroll
        for (int r = 0; r < 4; ++r) {
            int n = base + r0 + quad * 4 + r;
            if (n < N) {
                float v = fmaxf(acc[r] + bias_l, 0.f);
                h1h[(size_t)n * DIM + wid * 16 + sub] = __float2half(v);
            }
        }
    }
}

// Set2Set (3 steps) + head. GPB=2 graphs/block, two waves per graph
// (512 blocks -> 2 blocks/CU). Unchanged from R15/R16.
__global__ __launch_bounds__(256)
void set2set_fused_kernel(const __half* __restrict__ h1h,
                          const float* __restrict__ W_ih,
                          const float* __restrict__ W_hh,
                          const float* __restrict__ b_ih,
                          const float* __restrict__ b_hh,
                          const int* __restrict__ startb,
                          const int* __restrict__ endb,
                          const float* __restrict__ lin1_W,
                          const float* __restrict__ lin1_b,
                          const float* __restrict__ lin2_W,
                          const float* __restrict__ lin2_b,
                          float* __restrict__ out) {
    int g0  = blockIdx.x * GPB;
    int tid = threadIdx.x;
    __shared__ __align__(16) float qsbuf[GPB][2 * DIM];
    __shared__ float csbuf[GPB][DIM];
    __shared__ float gatesL[GPB][4 * DIM];
    __shared__ float scL[GPB][SCCAP];
    __shared__ float pmax[GPB][2];
    __shared__ float pden[GPB][2];
    __shared__ __align__(16) float4 pr[GPB][2][16];

    int wid  = tid >> 6;
    int myg  = wid >> 1;
    int wh   = wid & 1;
    int lane = tid & 63;
    int stg  = startb[g0 + myg];
    int cntg = endb[g0 + myg] - stg;
    if (cntg < 0) cntg = 0;

    for (int f = tid; f < GPB * 2 * DIM; f += 256) ((float*)qsbuf)[f] = 0.f;
    for (int f = tid; f < GPB * DIM; f += 256) ((float*)csbuf)[f] = 0.f;
    float bias_t = b_ih[tid] + b_hh[tid];
    __syncthreads();

    int sub   = lane & 15;
    int jslot = lane >> 4;
    int i0    = wh * 4 + jslot;

    for (int step = 0; step < STEPS; ++step) {
        {
            float a0 = bias_t, a1 = bias_t;
            const float4* wi = (const float4*)(W_ih + (size_t)tid * 2 * DIM);
            const float4* q0 = (const float4*)qsbuf[0];
            const float4* q1 = (const float4*)qsbuf[1];
            #pragma unroll 8
            for (int k = 0; k < 2 * DIM / 4; ++k) {
                float4 w = wi[k];
                float4 v0 = q0[k], v1 = q1[k];
                a0 += w.x * v0.x + w.y * v0.y + w.z * v0.z + w.w * v0.w;
                a1 += w.x * v1.x + w.y * v1.y + w.z * v1.z + w.w * v1.w;
            }
            const float4* wh4 = (const float4*)(W_hh + (size_t)tid * DIM);
            #pragma unroll 8
            for (int k = 0; k < DIM / 4; ++k) {
                float4 w = wh4[k];
                float4 v0 = q0[k], v1 = q1[k];
                a0 += w.x * v0.x + w.y * v0.y + w.z * v0.z + w.w * v0.w;
                a1 += w.x * v1.x + w.y * v1.y + w.z * v1.z + w.w * v1.w;
            }
            gatesL[0][tid] = a0; gatesL[1][tid] = a1;
        }
        __syncthreads();
        if (tid < GPB * DIM) {
            int g = tid >> 6, d = tid & 63;
            float ig = gatesL[g][d];
            float fg = gatesL[g][DIM + d];
            float gg = gatesL[g][2 * DIM + d];
            float og = gatesL[g][3 * DIM + d];
            float si = 1.f / (1.f + __expf(-ig));
            float sf = 1.f / (1.f + __expf(-fg));
            float so = 1.f / (1.f + __expf(-og));
            float cn = sf * csbuf[g][d] + si * tanhf(gg);
            float hn = so * tanhf(cn);
            csbuf[g][d] = cn;
            qsbuf[g][d] = hn;
        }
        __syncthreads();

        const float4 q4 = *(const float4*)(&qsbuf[myg][4 * sub]);

        float gmax = -INFINITY;
        for (int i = i0; i < cntg; i += 8) {
            const __half2* p =
                (const __half2*)(h1h + (size_t)(stg + i) * DIM + 4 * sub);
            float2 f0 = __half22float2(p[0]), f1 = __half22float2(p[1]);
            float pdot = f0.x * q4.x + f0.y * q4.y + f1.x * q4.z + f1.y * q4.w;
            pdot += __shfl_xor(pdot, 1, 64);
            pdot += __shfl_xor(pdot, 2, 64);
            pdot += __shfl_xor(pdot, 4, 64);
            pdot += __shfl_xor(pdot, 8, 64);
            if (sub == 0 && i < SCCAP) scL[myg][i] = pdot;
            gmax = fmaxf(gmax, pdot);
        }
        gmax = fmaxf(gmax, __shfl_xor(gmax, 16, 64));
        gmax = fmaxf(gmax, __shfl_xor(gmax, 32, 64));
        if (lane == 0) pmax[myg][wh] = gmax;
        __syncthreads();
        float m = fmaxf(pmax[myg][0], pmax[myg][1]);

        float4 racc = {0.f, 0.f, 0.f, 0.f};
        float den = 0.f;
        for (int i = i0; i < cntg; i += 8) {
            const __half2* p =
                (const __half2*)(h1h + (size_t)(stg + i) * DIM + 4 * sub);
            float2 f0 = __half22float2(p[0]), f1 = __half22float2(p[1]);
            float pdot;
            if (i < SCCAP) {
                pdot = scL[myg][i];
            } else {
                pdot = f0.x * q4.x + f0.y * q4.y + f1.x * q4.z + f1.y * q4.w;
                pdot += __shfl_xor(pdot, 1, 64);
                pdot += __shfl_xor(pdot, 2, 64);
                pdot += __shfl_xor(pdot, 4, 64);
                pdot += __shfl_xor(pdot, 8, 64);
            }
            float w = __expf(pdot - m);
            if (sub == 0) den += w;
            racc.x += w * f0.x; racc.y += w * f0.y;
            racc.z += w * f1.x; racc.w += w * f1.y;
        }
        racc.x += __shfl_xor(racc.x, 16, 64); racc.y += __shfl_xor(racc.y, 16, 64);
        racc.z += __shfl_xor(racc.z, 16, 64); racc.w += __shfl_xor(racc.w, 16, 64);
        racc.x += __shfl_xor(racc.x, 32, 64); racc.y += __shfl_xor(racc.y, 32, 64);
        racc.z += __shfl_xor(racc.z, 32, 64); racc.w += __shfl_xor(racc.w, 32, 64);
        den += __shfl_xor(den, 16, 64);
        den += __shfl_xor(den, 32, 64);
        if (jslot == 0) pr[myg][wh][sub] = racc;
        if (lane == 0) pden[myg][wh] = den;
        __syncthreads();
        if (wh == 0 && jslot == 0) {
            float4 rA = pr[myg][0][sub];
            float4 rB = pr[myg][1][sub];
            float dt = pden[myg][0] + pden[myg][1];
            if (dt == 0.f) dt = 1.f;
            float4 rv;
            rv.x = (rA.x + rB.x) / dt; rv.y = (rA.y + rB.y) / dt;
            rv.z = (rA.z + rB.z) / dt; rv.w = (rA.w + rB.w) / dt;
            *(float4*)(&qsbuf[myg][DIM + 4 * sub]) = rv;
        }
        __syncthreads();
    }

    if (wh == 0) {
        float acc = lin1_b[lane];
        const float* qv = qsbuf[myg];
        #pragma unroll 8
        for (int k = 0; k < 2 * DIM; ++k)
            acc += qv[k] * lin1_W[k * DIM + lane];
        acc = fmaxf(acc, 0.f);
        float v = acc * lin2_W[lane];
        v = wave_sum(v);
        if (lane == 0) out[g0 + myg] = v + lin2_b[0];
    }
}

extern "C" void kernel_launch(void* const* d_in, const int* in_sizes, int n_in,
                              void* d_out, int out_size, void* d_ws, size_t ws_size,
                              hipStream_t stream) {
    const float* x      = (const float*)d_in[0];
    const int*   ei     = (const int*)d_in[1];
    const int*   batch  = (const int*)d_in[2];
    const float* lin0_W = (const float*)d_in[3];
    const float* lin0_b = (const float*)d_in[4];
    const float* gin_W  = (const float*)d_in[5];
    const float* gin_b  = (const float*)d_in[6];
    const float* W_ih   = (const float*)d_in[7];
    const float* W_hh   = (const float*)d_in[8];
    const float* b_ih   = (const float*)d_in[9];
    const float* b_hh   = (const float*)d_in[10];
    const float* lin1_W = (const float*)d_in[11];
    const float* lin1_b = (const float*)d_in[12];
    const float* lin2_W = (const float*)d_in[13];
    const float* lin2_b = (const float*)d_in[14];
    float* out = (float*)d_out;

    const int N = in_sizes[2];        // 100000 nodes
    const int E = in_sizes[1] / 2;    // 1600000 edges

    char* ws = (char*)d_ws;
    size_t off = 0;
    auto take = [&](size_t bytes) -> char* {
        char* p = ws + off;
        off += (bytes + 255) & ~(size_t)255;
        return p;
    };
    int nbuck = (N + (1 << BSHIFT) - 1) >> BSHIFT;        // 782

    __half*   h0h   = (__half*)take((size_t)N * DIM * 2);
    __half*   h1h   = (__half*)take((size_t)N * DIM * 2);
    unsigned* arena = (unsigned*)take((size_t)nbuck * BCAP * 4);
    // ---- zeroed region start ----
    int* startb = (int*)take((size_t)B_GRAPHS * 4);
    int* endb   = (int*)take((size_t)B_GRAPHS * 4);
    int* gcur   = (int*)take((size_t)NBUCK_MAX * 4);
    // ---- zeroed region end ----
    size_t zero_bytes = (size_t)((char*)gcur - (char*)startb) + NBUCK_MAX * 4;
    hipMemsetAsync(startb, 0, zero_bytes, stream);

    int nb4   = (N + 3) / 4;
    int nb256 = (N + 255) / 256;
    int fillB = (E + CHUNK_A - 1) / CHUNK_A;

    hipLaunchKernelGGL(prep_kernel, dim3(fillB + nb4 + nb256), dim3(256), 0, stream,
                       x, lin0_W, lin0_b, h0h, ei, E, batch, N,
                       gcur, arena, startb, endb, fillB, nb4, nbuck);
    hipLaunchKernelGGL(gin_bucket_kernel, dim3(nbuck), dim3(256), 0, stream,
                       h0h, arena, gcur, gin_W, gin_b, h1h, N);
    hipLaunchKernelGGL(set2set_fused_kernel, dim3(B_GRAPHS / GPB), dim3(256), 0, stream,
                       h1h, W_ih, W_hh, b_ih, b_hh, startb, endb,
                       lin1_W, lin1_b, lin2_W, lin2_b, out);
}